// Round 1
// baseline (491.162 us; speedup 1.0000x reference)
//
#include <hip/hip_runtime.h>

// H=256, B=512 graphs, N=200000 nodes, 3 steps.
#define HID 256
#define NG 512

__device__ __forceinline__ float sigmoidf_(float v) { return 1.f / (1.f + __expf(-v)); }

// ---------------------------------------------------------------------------
// Fused setup: blocks [0,2048) build Wcat/bcat, blocks [2048,2051) binary-search
// the per-graph start offsets. Removes one dispatch + runs both concurrently.
__global__ __launch_bounds__(256) void setup_kernel(
    const float* __restrict__ W_ih, const float* __restrict__ W_hh,
    const float* __restrict__ b_ih, const float* __restrict__ b_hh,
    float* __restrict__ Wcat, float* __restrict__ bcat,
    const int* __restrict__ batch, int n, int* __restrict__ starts)
{
    int b = blockIdx.x;
    if (b < 2048) {
        int idx = b * 256 + threadIdx.x;
        int k = idx & 511;
        float v = W_ih[idx];
        if (k < 256) v += W_hh[(idx >> 9) * 256 + k];
        Wcat[idx] = v;
        if (idx < 1024) bcat[idx] = b_ih[idx] + b_hh[idx];
    } else {
        int g = (b - 2048) * 256 + threadIdx.x;
        if (g > NG) return;
        if (g == NG) { starts[NG] = n; return; }
        int lo = 0, hi = n;
        while (lo < hi) {
            int mid = (lo + hi) >> 1;
            if (batch[mid] < g) lo = mid + 1; else hi = mid;
        }
        starts[g] = lo;
    }
}

// ---------------------------------------------------------------------------
// Fused LSTM cell + attention + readout. One block per graph, 512 threads
// (8 waves) so 2 blocks/CU = 16 waves/CU (launch_bounds caps VGPR<=128).
// Wave w owns 8-row chunks c ≡ w (mod 8); private online-softmax state in
// registers; q fragments read from LDS per chunk to stay under the VGPR cap.
__global__ __launch_bounds__(512, 4) void attn_kernel(
    const float* __restrict__ x, const int* __restrict__ starts,
    const float* __restrict__ gates_p,      // [4][512][1024] split-K partials
    const float* __restrict__ bcat, float* __restrict__ cs,
    float* __restrict__ qs, int step0)
{
    __shared__ __align__(16) float ql[HID];
    __shared__ __align__(16) float red[8][HID];
    __shared__ float mw[8], lw[8];

    const int g = blockIdx.x;
    const int tid = threadIdx.x;

    // ---- LSTM cell for hidden unit `tid` (gate order i,f,g,o), threads <256
    if (tid < 256) {
        float ig, fg, gg, og, cp;
        if (step0) {
            ig = bcat[tid]; fg = bcat[256 + tid]; gg = bcat[512 + tid]; og = bcat[768 + tid];
            cp = 0.f;
        } else {
            ig = bcat[tid]; fg = bcat[256 + tid]; gg = bcat[512 + tid]; og = bcat[768 + tid];
            const float* a = gates_p + (size_t)g * 1024;
            const size_t ss = (size_t)512 * 1024;
            #pragma unroll
            for (int z = 0; z < 4; ++z) {
                const float* az = a + z * ss;
                ig += az[tid]; fg += az[256 + tid]; gg += az[512 + tid]; og += az[768 + tid];
            }
            cp = cs[g * HID + tid];
        }
        float cn = sigmoidf_(fg) * cp + sigmoidf_(ig) * tanhf(gg);
        float h  = sigmoidf_(og) * tanhf(cn);
        cs[g * HID + tid] = cn;
        qs[(size_t)g * 512 + tid] = h;      // q_star[:, :256] = hs
        ql[tid] = h;
    }
    __syncthreads();

    const int s0 = starts[g];
    const int nn = starts[g + 1] - s0;
    if (nn <= 0) {
        if (tid < 256) qs[(size_t)g * 512 + HID + tid] = 0.f;
        return;
    }

    const int w = tid >> 6, lane = tid & 63;
    const int j = lane >> 3;        // row within 8-row chunk
    const int s = lane & 7;         // 16B column-group within row

    const float4* qp = (const float4*)&ql[s * 4];   // qp[k*8] = ql[k*32 + s*4]

    const int nch = (nn + 7) >> 3;          // 8-row chunks
    const int last = s0 + nn - 1;
    const float NEG = -3.402823466e38f;

    float m_run = NEG, l_run = 0.f;
    float4 racc[8] = {};
    float4 xc[8], xn[8];

    int c = w;
    if (c < nch) {
        int node = s0 + c * 8 + j; if (node > last) node = last;
        const float* bp = x + (size_t)node * HID + s * 4;
        #pragma unroll
        for (int k = 0; k < 8; ++k) xc[k] = *(const float4*)(bp + k * 32);
    }
    for (; c < nch; c += 8) {
        if (c + 8 < nch) {
            int node = s0 + (c + 8) * 8 + j; if (node > last) node = last;
            const float* bp = x + (size_t)node * HID + s * 4;
            #pragma unroll
            for (int k = 0; k < 8; ++k) xn[k] = *(const float4*)(bp + k * 32);
        }
        const bool valid = (c * 8 + j) < nn;   // j=0 always valid for c<nch

        float e = 0.f;
        #pragma unroll
        for (int k = 0; k < 8; ++k) {
            float4 q = qp[k * 8];
            e += xc[k].x * q.x + xc[k].y * q.y + xc[k].z * q.z + xc[k].w * q.w;
        }
        e += __shfl_xor(e, 1); e += __shfl_xor(e, 2); e += __shfl_xor(e, 4);
        e = valid ? e : NEG;

        float mc = e;
        mc = fmaxf(mc, __shfl_xor(mc, 8));
        mc = fmaxf(mc, __shfl_xor(mc, 16));
        mc = fmaxf(mc, __shfl_xor(mc, 32));
        float m_new = fmaxf(m_run, mc);        // finite: row j=0 is valid
        float alpha = __expf(m_run - m_new);   // first iter: expf(-3.4e38)=0
        float p = valid ? __expf(e - m_new) : 0.f;
        float ps = p;
        ps += __shfl_xor(ps, 8); ps += __shfl_xor(ps, 16); ps += __shfl_xor(ps, 32);
        l_run = l_run * alpha + ps;
        m_run = m_new;
        #pragma unroll
        for (int k = 0; k < 8; ++k) {
            racc[k].x = racc[k].x * alpha + p * xc[k].x;
            racc[k].y = racc[k].y * alpha + p * xc[k].y;
            racc[k].z = racc[k].z * alpha + p * xc[k].z;
            racc[k].w = racc[k].w * alpha + p * xc[k].w;
        }
        #pragma unroll
        for (int k = 0; k < 8; ++k) xc[k] = xn[k];
    }

    // fold racc across the 8 row-slots (lane bits 3..5); once per pass
    #pragma unroll
    for (int k = 0; k < 8; ++k) {
        racc[k].x += __shfl_xor(racc[k].x, 8);
        racc[k].y += __shfl_xor(racc[k].y, 8);
        racc[k].z += __shfl_xor(racc[k].z, 8);
        racc[k].w += __shfl_xor(racc[k].w, 8);
        racc[k].x += __shfl_xor(racc[k].x, 16);
        racc[k].y += __shfl_xor(racc[k].y, 16);
        racc[k].z += __shfl_xor(racc[k].z, 16);
        racc[k].w += __shfl_xor(racc[k].w, 16);
        racc[k].x += __shfl_xor(racc[k].x, 32);
        racc[k].y += __shfl_xor(racc[k].y, 32);
        racc[k].z += __shfl_xor(racc[k].z, 32);
        racc[k].w += __shfl_xor(racc[k].w, 32);
    }
    if (j == 0) {
        #pragma unroll
        for (int k = 0; k < 8; ++k) *(float4*)&red[w][k * 32 + s * 4] = racc[k];
        if (s == 0) { mw[w] = m_run; lw[w] = l_run; }
    }
    __syncthreads();

    // merge the 8 wave-states (empty wave: m=NEG -> factor exp(NEG-M)=0)
    if (tid < 256) {
        float M = NEG;
        #pragma unroll
        for (int v = 0; v < 8; ++v) M = fmaxf(M, mw[v]);
        float L = 0.f, r = 0.f;
        #pragma unroll
        for (int v = 0; v < 8; ++v) {
            float f = __expf(mw[v] - M);
            L += lw[v] * f;
            r += red[v][tid] * f;
        }
        qs[(size_t)g * 512 + HID + tid] = r / L;     // q_star[:, 256:512] = r
    }
}

// ---------------------------------------------------------------------------
// Cp[z][M x N] = A[M x K-slice] * B[N x K-slice]^T ; 64x64 tile, 4x4 micro,
// b128 LDS reads both operands, global prefetch. grid (N/64, M/64, S).
__global__ __launch_bounds__(256) void gemm_splitk(
    const float* __restrict__ A, int lda,
    const float* __restrict__ B, int ldb,
    float* __restrict__ Cp, int ldc, int KS, size_t slice_stride)
{
    __shared__ float As[16][76];
    __shared__ float Bs[16][76];
    const int tid = threadIdx.x;
    const int tx = tid & 15, ty = tid >> 4;
    const int m0 = blockIdx.y * 64, n0 = blockIdx.x * 64;
    const int kb = blockIdx.z * KS;
    const int r = tid >> 2, kc = (tid & 3) << 2;
    float acc[4][4] = {};

    const float* Ap = &A[(size_t)(m0 + r) * lda + kb + kc];
    const float* Bp = &B[(size_t)(n0 + r) * ldb + kb + kc];
    float4 av = *(const float4*)Ap;
    float4 bv = *(const float4*)Bp;

    for (int k0 = 0; k0 < KS; k0 += 16) {
        As[kc + 0][r] = av.x; As[kc + 1][r] = av.y; As[kc + 2][r] = av.z; As[kc + 3][r] = av.w;
        Bs[kc + 0][r] = bv.x; Bs[kc + 1][r] = bv.y; Bs[kc + 2][r] = bv.z; Bs[kc + 3][r] = bv.w;
        __syncthreads();
        if (k0 + 16 < KS) {
            av = *(const float4*)(Ap + k0 + 16);
            bv = *(const float4*)(Bp + k0 + 16);
        }
        #pragma unroll
        for (int kk = 0; kk < 16; ++kk) {
            float4 a = *(const float4*)&As[kk][ty << 2];
            float4 b = *(const float4*)&Bs[kk][tx << 2];
            acc[0][0] += a.x * b.x; acc[0][1] += a.x * b.y; acc[0][2] += a.x * b.z; acc[0][3] += a.x * b.w;
            acc[1][0] += a.y * b.x; acc[1][1] += a.y * b.y; acc[1][2] += a.y * b.z; acc[1][3] += a.y * b.w;
            acc[2][0] += a.z * b.x; acc[2][1] += a.z * b.y; acc[2][2] += a.z * b.z; acc[2][3] += a.z * b.w;
            acc[3][0] += a.w * b.x; acc[3][1] += a.w * b.y; acc[3][2] += a.w * b.z; acc[3][3] += a.w * b.w;
        }
        __syncthreads();
    }
    float* out = Cp + blockIdx.z * slice_stride;
    #pragma unroll
    for (int i = 0; i < 4; ++i) {
        float4 o = make_float4(acc[i][0], acc[i][1], acc[i][2], acc[i][3]);
        *(float4*)&out[(size_t)(m0 + ty * 4 + i) * ldc + n0 + (tx << 2)] = o;
    }
}

// ---------------------------------------------------------------------------
__global__ __launch_bounds__(256) void finalize_out(
    const float* __restrict__ op, const float* __restrict__ b_out,
    float* __restrict__ out)
{
    int i = blockIdx.x * 256 + threadIdx.x;
    if (i < 512 * 256) {
        float v = op[i] + op[131072 + i] + op[262144 + i] + op[393216 + i] + b_out[i & 255];
        out[i] = v;
    }
}

// ---------------------------------------------------------------------------
extern "C" void kernel_launch(void* const* d_in, const int* in_sizes, int n_in,
                              void* d_out, int out_size, void* d_ws, size_t ws_size,
                              hipStream_t stream)
{
    const float* x     = (const float*)d_in[0];
    const int*   batch = (const int*)d_in[1];
    const float* W_ih  = (const float*)d_in[2];
    const float* W_hh  = (const float*)d_in[3];
    const float* b_ih  = (const float*)d_in[4];
    const float* b_hh  = (const float*)d_in[5];
    const float* W_out = (const float*)d_in[6];
    const float* b_out = (const float*)d_in[7];
    float* out = (float*)d_out;
    const int n = in_sizes[1];
    (void)n_in; (void)out_size; (void)ws_size;

    char* ws = (char*)d_ws;
    float* qs      = (float*)(ws);                  // [512][512]
    float* cs      = (float*)(ws + 0x100000);       // [512][256]
    float* gates_p = (float*)(ws + 0x180000);       // [4][512][1024]
    float* Wcat    = (float*)(ws + 0x980000);       // [1024][512]
    float* bcat    = (float*)(ws + 0xB80000);       // [1024]
    int*   starts  = (int*)  (ws + 0xB81000);       // [513]
    float* out_p   = (float*)(ws + 0xB90000);       // [4][512][256]

    setup_kernel<<<2051, 256, 0, stream>>>(W_ih, W_hh, b_ih, b_hh, Wcat, bcat,
                                           batch, n, starts);

    for (int step = 0; step < 3; ++step) {
        if (step > 0) {
            gemm_splitk<<<dim3(16, 8, 4), 256, 0, stream>>>(
                qs, 512, Wcat, 512, gates_p, 1024, 128, (size_t)512 * 1024);
        }
        attn_kernel<<<NG, 512, 0, stream>>>(
            x, starts, gates_p, bcat, cs, qs, step == 0);
    }
    gemm_splitk<<<dim3(4, 8, 4), 256, 0, stream>>>(
        qs, 512, W_out, 512, out_p, 256, 128, (size_t)512 * 256);
    finalize_out<<<512, 256, 0, stream>>>(out_p, b_out, out);
}

// Round 2
// 412.117 us; speedup vs baseline: 1.1918x; 1.1918x over previous
//
#include <hip/hip_runtime.h>

// H=256, B=512 graphs, N=200000 nodes, 3 steps.
#define HID 256
#define NG 512

__device__ __forceinline__ float sigmoidf_(float v) { return 1.f / (1.f + __expf(-v)); }

// ---------------------------------------------------------------------------
// Fused setup: blocks [0,2048) build Wcat/bcat, blocks [2048,2051) binary-search
// the per-graph start offsets.
__global__ __launch_bounds__(256) void setup_kernel(
    const float* __restrict__ W_ih, const float* __restrict__ W_hh,
    const float* __restrict__ b_ih, const float* __restrict__ b_hh,
    float* __restrict__ Wcat, float* __restrict__ bcat,
    const int* __restrict__ batch, int n, int* __restrict__ starts)
{
    int b = blockIdx.x;
    if (b < 2048) {
        int idx = b * 256 + threadIdx.x;
        int k = idx & 511;
        float v = W_ih[idx];
        if (k < 256) v += W_hh[(idx >> 9) * 256 + k];
        Wcat[idx] = v;
        if (idx < 1024) bcat[idx] = b_ih[idx] + b_hh[idx];
    } else {
        int g = (b - 2048) * 256 + threadIdx.x;
        if (g > NG) return;
        if (g == NG) { starts[NG] = n; return; }
        int lo = 0, hi = n;
        while (lo < hi) {
            int mid = (lo + hi) >> 1;
            if (batch[mid] < g) lo = mid + 1; else hi = mid;
        }
        starts[g] = lo;
    }
}

// ---------------------------------------------------------------------------
// Fused LSTM cell + attention + readout. One block per graph, 4 waves.
// Wave w owns 8-row chunks c ≡ w (mod 4). Depth-2 software pipeline with a
// 3-buffer (P/Q/R) round-robin so each compute waits only on the OLDEST 8
// loads (compiler emits counted vmcnt, never a full drain in steady state).
// Online-softmax state entirely in registers; 4 wave-states merged at end.

#define LOADB(BUF, CIDX) do {                                               \
    int node_ = s0 + (CIDX) * 8 + j; if (node_ > last) node_ = last;        \
    const float* bp_ = x + (size_t)node_ * HID + s * 4;                     \
    _Pragma("unroll")                                                       \
    for (int k = 0; k < 8; ++k) BUF[k] = *(const float4*)(bp_ + k * 32);    \
} while (0)

#define COMPUTE(BUF, CIDX) do {                                             \
    const bool valid_ = ((CIDX) * 8 + j) < nn;                              \
    float e_ = 0.f;                                                         \
    _Pragma("unroll")                                                       \
    for (int k = 0; k < 8; ++k)                                             \
        e_ += BUF[k].x * qf[k].x + BUF[k].y * qf[k].y                       \
            + BUF[k].z * qf[k].z + BUF[k].w * qf[k].w;                      \
    e_ += __shfl_xor(e_, 1); e_ += __shfl_xor(e_, 2); e_ += __shfl_xor(e_, 4); \
    e_ = valid_ ? e_ : NEG;                                                 \
    float mc_ = e_;                                                         \
    mc_ = fmaxf(mc_, __shfl_xor(mc_, 8));                                   \
    mc_ = fmaxf(mc_, __shfl_xor(mc_, 16));                                  \
    mc_ = fmaxf(mc_, __shfl_xor(mc_, 32));                                  \
    float mnew_ = fmaxf(m_run, mc_);                                        \
    float alpha_ = __expf(m_run - mnew_);                                   \
    float p_ = valid_ ? __expf(e_ - mnew_) : 0.f;                           \
    float ps_ = p_;                                                         \
    ps_ += __shfl_xor(ps_, 8); ps_ += __shfl_xor(ps_, 16); ps_ += __shfl_xor(ps_, 32); \
    l_run = l_run * alpha_ + ps_;                                           \
    m_run = mnew_;                                                          \
    _Pragma("unroll")                                                       \
    for (int k = 0; k < 8; ++k) {                                           \
        racc[k].x = racc[k].x * alpha_ + p_ * BUF[k].x;                     \
        racc[k].y = racc[k].y * alpha_ + p_ * BUF[k].y;                     \
        racc[k].z = racc[k].z * alpha_ + p_ * BUF[k].z;                     \
        racc[k].w = racc[k].w * alpha_ + p_ * BUF[k].w;                     \
    }                                                                       \
} while (0)

__global__ __launch_bounds__(256) void attn_kernel(
    const float* __restrict__ x, const int* __restrict__ starts,
    const float* __restrict__ gates_p,      // [4][512][1024] split-K partials
    const float* __restrict__ bcat, float* __restrict__ cs,
    float* __restrict__ qs, int step0)
{
    __shared__ __align__(16) float ql[HID];
    __shared__ __align__(16) float red[4][HID];
    __shared__ float mw[4], lw[4];

    const int g = blockIdx.x;
    const int tid = threadIdx.x;

    // ---- LSTM cell for hidden unit `tid` (gate order i,f,g,o)
    {
        float ig = bcat[tid], fg = bcat[256 + tid], gg = bcat[512 + tid], og = bcat[768 + tid];
        float cp = 0.f;
        if (!step0) {
            const float* a = gates_p + (size_t)g * 1024;
            const size_t ss = (size_t)512 * 1024;
            #pragma unroll
            for (int z = 0; z < 4; ++z) {
                const float* az = a + z * ss;
                ig += az[tid]; fg += az[256 + tid]; gg += az[512 + tid]; og += az[768 + tid];
            }
            cp = cs[g * HID + tid];
        }
        float cn = sigmoidf_(fg) * cp + sigmoidf_(ig) * tanhf(gg);
        float h  = sigmoidf_(og) * tanhf(cn);
        cs[g * HID + tid] = cn;
        qs[(size_t)g * 512 + tid] = h;      // q_star[:, :256] = hs
        ql[tid] = h;
    }

    const int s0 = starts[g];
    const int nn = starts[g + 1] - s0;
    if (nn <= 0) { qs[(size_t)g * 512 + HID + tid] = 0.f; return; }
    __syncthreads();

    const int w = tid >> 6, lane = tid & 63;
    const int j = lane >> 3;        // row within 8-row chunk
    const int s = lane & 7;         // 16B column-group within row

    float4 qf[8];
    #pragma unroll
    for (int k = 0; k < 8; ++k) qf[k] = *(const float4*)&ql[k * 32 + s * 4];

    const int nch = (nn + 7) >> 3;          // 8-row chunks
    const int last = s0 + nn - 1;
    const float NEG = -3.402823466e38f;

    float m_run = NEG, l_run = 0.f;
    float4 racc[8] = {};
    float4 P[8], Q[8], R[8];

    // wave's chunks: w, w+4, w+8, ... ; pipeline depth 2 (P,Q in flight ahead)
    int c = w;
    if (c < nch)     LOADB(P, c);
    if (c + 4 < nch) LOADB(Q, c + 4);
    for (; c < nch; c += 12) {
        if (c + 8 < nch)  LOADB(R, c + 8);
        COMPUTE(P, c);
        if (c + 4 >= nch) break;
        if (c + 12 < nch) LOADB(P, c + 12);
        COMPUTE(Q, c + 4);
        if (c + 8 >= nch) break;
        if (c + 16 < nch) LOADB(Q, c + 16);
        COMPUTE(R, c + 8);
    }

    // fold racc across the 8 row-slots (lane bits 3..5); once per pass
    #pragma unroll
    for (int k = 0; k < 8; ++k) {
        racc[k].x += __shfl_xor(racc[k].x, 8);
        racc[k].y += __shfl_xor(racc[k].y, 8);
        racc[k].z += __shfl_xor(racc[k].z, 8);
        racc[k].w += __shfl_xor(racc[k].w, 8);
        racc[k].x += __shfl_xor(racc[k].x, 16);
        racc[k].y += __shfl_xor(racc[k].y, 16);
        racc[k].z += __shfl_xor(racc[k].z, 16);
        racc[k].w += __shfl_xor(racc[k].w, 16);
        racc[k].x += __shfl_xor(racc[k].x, 32);
        racc[k].y += __shfl_xor(racc[k].y, 32);
        racc[k].z += __shfl_xor(racc[k].z, 32);
        racc[k].w += __shfl_xor(racc[k].w, 32);
    }
    if (j == 0) {
        #pragma unroll
        for (int k = 0; k < 8; ++k) *(float4*)&red[w][k * 32 + s * 4] = racc[k];
        if (s == 0) { mw[w] = m_run; lw[w] = l_run; }
    }
    __syncthreads();

    // merge the 4 wave-states (empty wave: m=NEG -> factor exp(NEG-M)=0)
    float M = fmaxf(fmaxf(mw[0], mw[1]), fmaxf(mw[2], mw[3]));
    float f0 = __expf(mw[0] - M), f1 = __expf(mw[1] - M);
    float f2 = __expf(mw[2] - M), f3 = __expf(mw[3] - M);
    float L = lw[0] * f0 + lw[1] * f1 + lw[2] * f2 + lw[3] * f3;
    float r = red[0][tid] * f0 + red[1][tid] * f1 + red[2][tid] * f2 + red[3][tid] * f3;
    qs[(size_t)g * 512 + HID + tid] = r / L;     // q_star[:, 256:512] = r
}

// ---------------------------------------------------------------------------
// Cp[z][M x N] = A[M x K-slice] * B[N x K-slice]^T ; 64x64 tile, 4x4 micro,
// b128 LDS reads both operands, global prefetch. grid (N/64, M/64, S).
__global__ __launch_bounds__(256) void gemm_splitk(
    const float* __restrict__ A, int lda,
    const float* __restrict__ B, int ldb,
    float* __restrict__ Cp, int ldc, int KS, size_t slice_stride)
{
    __shared__ float As[16][76];
    __shared__ float Bs[16][76];
    const int tid = threadIdx.x;
    const int tx = tid & 15, ty = tid >> 4;
    const int m0 = blockIdx.y * 64, n0 = blockIdx.x * 64;
    const int kb = blockIdx.z * KS;
    const int r = tid >> 2, kc = (tid & 3) << 2;
    float acc[4][4] = {};

    const float* Ap = &A[(size_t)(m0 + r) * lda + kb + kc];
    const float* Bp = &B[(size_t)(n0 + r) * ldb + kb + kc];
    float4 av = *(const float4*)Ap;
    float4 bv = *(const float4*)Bp;

    for (int k0 = 0; k0 < KS; k0 += 16) {
        As[kc + 0][r] = av.x; As[kc + 1][r] = av.y; As[kc + 2][r] = av.z; As[kc + 3][r] = av.w;
        Bs[kc + 0][r] = bv.x; Bs[kc + 1][r] = bv.y; Bs[kc + 2][r] = bv.z; Bs[kc + 3][r] = bv.w;
        __syncthreads();
        if (k0 + 16 < KS) {
            av = *(const float4*)(Ap + k0 + 16);
            bv = *(const float4*)(Bp + k0 + 16);
        }
        #pragma unroll
        for (int kk = 0; kk < 16; ++kk) {
            float4 a = *(const float4*)&As[kk][ty << 2];
            float4 b = *(const float4*)&Bs[kk][tx << 2];
            acc[0][0] += a.x * b.x; acc[0][1] += a.x * b.y; acc[0][2] += a.x * b.z; acc[0][3] += a.x * b.w;
            acc[1][0] += a.y * b.x; acc[1][1] += a.y * b.y; acc[1][2] += a.y * b.z; acc[1][3] += a.y * b.w;
            acc[2][0] += a.z * b.x; acc[2][1] += a.z * b.y; acc[2][2] += a.z * b.z; acc[2][3] += a.z * b.w;
            acc[3][0] += a.w * b.x; acc[3][1] += a.w * b.y; acc[3][2] += a.w * b.z; acc[3][3] += a.w * b.w;
        }
        __syncthreads();
    }
    float* out = Cp + blockIdx.z * slice_stride;
    #pragma unroll
    for (int i = 0; i < 4; ++i) {
        float4 o = make_float4(acc[i][0], acc[i][1], acc[i][2], acc[i][3]);
        *(float4*)&out[(size_t)(m0 + ty * 4 + i) * ldc + n0 + (tx << 2)] = o;
    }
}

// ---------------------------------------------------------------------------
__global__ __launch_bounds__(256) void finalize_out(
    const float* __restrict__ op, const float* __restrict__ b_out,
    float* __restrict__ out)
{
    int i = blockIdx.x * 256 + threadIdx.x;
    if (i < 512 * 256) {
        float v = op[i] + op[131072 + i] + op[262144 + i] + op[393216 + i] + b_out[i & 255];
        out[i] = v;
    }
}

// ---------------------------------------------------------------------------
extern "C" void kernel_launch(void* const* d_in, const int* in_sizes, int n_in,
                              void* d_out, int out_size, void* d_ws, size_t ws_size,
                              hipStream_t stream)
{
    const float* x     = (const float*)d_in[0];
    const int*   batch = (const int*)d_in[1];
    const float* W_ih  = (const float*)d_in[2];
    const float* W_hh  = (const float*)d_in[3];
    const float* b_ih  = (const float*)d_in[4];
    const float* b_hh  = (const float*)d_in[5];
    const float* W_out = (const float*)d_in[6];
    const float* b_out = (const float*)d_in[7];
    float* out = (float*)d_out;
    const int n = in_sizes[1];
    (void)n_in; (void)out_size; (void)ws_size;

    char* ws = (char*)d_ws;
    float* qs      = (float*)(ws);                  // [512][512]
    float* cs      = (float*)(ws + 0x100000);       // [512][256]
    float* gates_p = (float*)(ws + 0x180000);       // [4][512][1024]
    float* Wcat    = (float*)(ws + 0x980000);       // [1024][512]
    float* bcat    = (float*)(ws + 0xB80000);       // [1024]
    int*   starts  = (int*)  (ws + 0xB81000);       // [513]
    float* out_p   = (float*)(ws + 0xB90000);       // [4][512][256]

    setup_kernel<<<2051, 256, 0, stream>>>(W_ih, W_hh, b_ih, b_hh, Wcat, bcat,
                                           batch, n, starts);

    for (int step = 0; step < 3; ++step) {
        if (step > 0) {
            gemm_splitk<<<dim3(16, 8, 4), 256, 0, stream>>>(
                qs, 512, Wcat, 512, gates_p, 1024, 128, (size_t)512 * 1024);
        }
        attn_kernel<<<NG, 256, 0, stream>>>(
            x, starts, gates_p, bcat, cs, qs, step == 0);
    }
    gemm_splitk<<<dim3(4, 8, 4), 256, 0, stream>>>(
        qs, 512, W_out, 512, out_p, 256, 128, (size_t)512 * 256);
    finalize_out<<<512, 256, 0, stream>>>(out_p, b_out, out);
}